// Round 13
// baseline (508.638 us; speedup 1.0000x reference)
//
#include <hip/hip_runtime.h>
#include <math.h>

// Non-local attention: X [8, 64, 64, 64] fp32.
// Per batch b: Q=K=V = X_b^T  [S=4096, D=64];  out = softmax(Q K^T) V, stored [b][c][s].
//
// R13 = R10 loop (compiler-scheduled; beats R11/R12 manual pipelines) + occupancy x2:
//  - split-K x8 -> 4096 blocks = 16 blocks/CU (thread-cap max)
//  - LDS 17408 -> 4608 B (epilogue transposed in four 16-channel chunks over sP)
//  - __launch_bounds__(128,8): VGPR cap 64 (R10 measured 60)
// Fragment-order global K/V streams, raw v_exp_f32 softmax, fixed C-S bound in C-init.

#define SEQ 4096
#define DIM 64
#define LDB 72
#define LDO 68
#define LDS2 68
#define NSPLIT 8
#define QSCALE 1.2011224087864498f   // sqrt(log2(e))

typedef __attribute__((ext_vector_type(8))) short  short8;
typedef __attribute__((ext_vector_type(4))) float  f32x4;

__device__ __forceinline__ unsigned short f2bf(float f) {
    union { float f; unsigned int u; } x; x.f = f;
    unsigned int u = x.u + 0x7FFFu + ((x.u >> 16) & 1u);
    return (unsigned short)(u >> 16);
}
__device__ __forceinline__ float bf2f(unsigned short h) {
    union { unsigned int u; float f; } x; x.u = ((unsigned int)h) << 16; return x.f;
}
__device__ __forceinline__ float fast_exp2(float x) {
#if __has_builtin(__builtin_amdgcn_exp2f)
    return __builtin_amdgcn_exp2f(x);
#else
    float r;
    asm("v_exp_f32 %0, %1\n\ts_nop 0" : "=v"(r) : "v"(x));
    return r;
#endif
}
__device__ __forceinline__ float fast_rcp(float x) {
#if __has_builtin(__builtin_amdgcn_rcpf)
    return __builtin_amdgcn_rcpf(x);
#else
    return 1.f / x;
#endif
}

// ---------------- prepass: fragment-order bf16 arrays + scaled norms + max partials ----
__global__ __launch_bounds__(256) void prepass4(const float* __restrict__ X,
                                                unsigned short* __restrict__ Kf,
                                                unsigned short* __restrict__ Vf,
                                                float* __restrict__ Norms,
                                                float* __restrict__ MaxPart) {
    __shared__ __align__(16) unsigned short sT[64 * LDS2];    // scaled [m][c]
    __shared__ __align__(16) unsigned short sVu[64 * LDS2];   // unscaled [c][m]
    __shared__ float sRed[4];
    const int b = blockIdx.y, m0 = blockIdx.x * 64;
    const float* Xb = X + (size_t)b * DIM * SEQ;
    const int t = threadIdx.x, w = t >> 6;
    const int mw = t & 15, cg = t >> 4;

    #pragma unroll
    for (int cr = 0; cr < 4; ++cr) {
        const int c = cg * 4 + cr;
        const f32x4 v = *(const f32x4*)(Xb + (size_t)c * SEQ + m0 + 4 * mw);
        *(ushort4*)(sVu + c * LDS2 + 4 * mw) =
            make_ushort4(f2bf(v.x), f2bf(v.y), f2bf(v.z), f2bf(v.w));
        sT[(4 * mw + 0) * LDS2 + c] = f2bf(v.x * QSCALE);
        sT[(4 * mw + 1) * LDS2 + c] = f2bf(v.y * QSCALE);
        sT[(4 * mw + 2) * LDS2 + c] = f2bf(v.z * QSCALE);
        sT[(4 * mw + 3) * LDS2 + c] = f2bf(v.w * QSCALE);
    }
    __syncthreads();
    const int m = t >> 2, ck = t & 3;   // m: key row (for Kf) AND chan row (for Vf)

    const short8 a0 = *(const short8*)(sT + m * LDS2 + ck * 16);
    const short8 a1 = *(const short8*)(sT + m * LDS2 + ck * 16 + 8);
    {
        const size_t base = (size_t)b * 262144 + (size_t)(m0 >> 5) * 2048;  // shorts
        #pragma unroll
        for (int j = 0; j < 2; ++j) {
            const int chunk = 2 * ck + j;
            const int tile = m >> 5, mt = (m >> 4) & 1;
            const int quad = chunk & 3, ks = chunk >> 2;
            const size_t off = base + (size_t)(tile * 4 + mt * 2 + ks) * 512
                                    + (size_t)(quad * 16 + (m & 15)) * 8;
            *(short8*)(Kf + off) = j ? a1 : a0;
        }
    }
    float s = 0.f;
    #pragma unroll
    for (int i = 0; i < 8; ++i) {
        const float f0 = bf2f((unsigned short)a0[i]);
        const float f1 = bf2f((unsigned short)a1[i]);
        s += f0 * f0 + f1 * f1;
    }
    s += __shfl_xor(s, 1);
    s += __shfl_xor(s, 2);
    const float nm = sqrtf(s);
    if (ck == 0) Norms[(size_t)b * SEQ + m0 + m] = nm;

    const short8 v0 = *(const short8*)(sVu + m * LDS2 + ck * 16);
    const short8 v1 = *(const short8*)(sVu + m * LDS2 + ck * 16 + 8);
    {
        const size_t base = (size_t)b * 262144;
        #pragma unroll
        for (int j = 0; j < 2; ++j) {
            const int chunk = 2 * ck + j;
            const int tile = chunk >> 2, quad = chunk & 3;
            const size_t off = base + (size_t)((m0 >> 5) + tile) * 2048
                                    + (size_t)((m >> 4) * 64 + quad * 16 + (m & 15)) * 8;
            *(short8*)(Vf + off) = j ? v1 : v0;
        }
    }

    float mx = nm;
    #pragma unroll
    for (int d = 4; d < 64; d <<= 1) mx = fmaxf(mx, __shfl_xor(mx, d));
    if ((t & 63) == 0) sRed[w] = mx;
    __syncthreads();
    if (t == 0)
        MaxPart[b * 64 + blockIdx.x] =
            fmaxf(fmaxf(sRed[0], sRed[1]), fmaxf(sRed[2], sRed[3]));
}

// BN=32 flash kernel, 2 waves x 32 Q rows, split-K x8. Fragment-order global K/V.
// LDS 4608 B: sP (wave-private P strips, 4KB) overlaid by the 16-channel epilogue buffer.
template <bool PARTIAL>
__global__ __launch_bounds__(128, 8) void attn_split4(const unsigned short* __restrict__ Kf,
                                                      const unsigned short* __restrict__ Vf,
                                                      const float* __restrict__ Norms,
                                                      const float* __restrict__ MaxPart,
                                                      unsigned short* __restrict__ Obf,  // PARTIAL
                                                      float* __restrict__ Lbase,         // PARTIAL
                                                      float* __restrict__ Out,           // !PARTIAL
                                                      int niter) {
    __shared__ __align__(16) unsigned char smem[4608];
    unsigned short* sP = (unsigned short*)smem;   // [wave][row n 0..31][32 shorts] = 4KB
    float*          sOc = (float*)smem;           // epilogue overlay: 16 ch x LDO fp32 (4352B)

    const int tid  = threadIdx.x;
    const int lane = tid & 63;
    const int w    = tid >> 6;
    const int l15  = lane & 15;
    const int quad = lane >> 4;

    const int b   = blockIdx.y;
    const int s0  = blockIdx.x * 64;
    const int h   = blockIdx.z;
    const int kt0 = h * niter;
    const unsigned short* Kfb = Kf + (size_t)b * 262144;
    const unsigned short* Vfb = Vf + (size_t)b * 262144;

    float mxn = MaxPart[b * 64 + lane];
    #pragma unroll
    for (int d = 1; d < 64; d <<= 1) mxn = fmaxf(mxn, __shfl_xor(mxn, d));

    // Q frags from Kf (scaled): row = s0+32w+16qt+l15 -> tile=(s0+32w)>>5, mt=qt
    short8 qf[2][2];
    f32x4 cin[2];
    const int qtile = (s0 + 32 * w) >> 5;
    #pragma unroll
    for (int qt = 0; qt < 2; ++qt) {
        #pragma unroll
        for (int ks = 0; ks < 2; ++ks)
            qf[qt][ks] = *(const short8*)(Kfb + (size_t)(qtile * 4 + qt * 2 + ks) * 512 + lane * 8);
        const float mrow = Norms[(size_t)b * SEQ + s0 + 32 * w + 16 * qt + l15] * mxn;
        cin[qt] = (f32x4){-mrow, -mrow, -mrow, -mrow};
    }

    f32x4 acc_o[2][4];
    #pragma unroll
    for (int qt = 0; qt < 2; ++qt)
        #pragma unroll
        for (int ct = 0; ct < 4; ++ct) acc_o[qt][ct] = (f32x4){0.f, 0.f, 0.f, 0.f};
    f32x4 lp4[2];
    lp4[0] = (f32x4){0.f, 0.f, 0.f, 0.f};
    lp4[1] = (f32x4){0.f, 0.f, 0.f, 0.f};

    // ---- P LDS addresses (wave-private; swizzle verified R8) ----
    const int vkey = (l15 & 3) ^ (l15 >> 2);
    unsigned short* const prow = sP + (w << 10) + (l15 << 5);     // +qt*512
    unsigned short* pw[2];
    #pragma unroll
    for (int mt = 0; mt < 2; ++mt)
        pw[mt] = prow + ((((2 * mt + (quad >> 1)) ^ vkey) << 3) + ((quad & 1) << 2));
    const unsigned short* pr = prow + ((quad ^ vkey) << 3);

    // ---- fragment stream pointers (lane-contiguous 1KB per load) ----
    const unsigned short* kp = Kfb + (size_t)kt0 * 2048 + lane * 8;
    const unsigned short* vp = Vfb + (size_t)kt0 * 2048 + lane * 8;

    for (int it = 0; it < niter; ++it) {
        short8 kf2[2][2], vf[4];
        #pragma unroll
        for (int mt = 0; mt < 2; ++mt)
            #pragma unroll
            for (int ks = 0; ks < 2; ++ks)
                kf2[mt][ks] = *(const short8*)(kp + (mt * 2 + ks) * 512);
        #pragma unroll
        for (int ct = 0; ct < 4; ++ct)
            vf[ct] = *(const short8*)(vp + ct * 512);

        // phase 1: all S-MFMAs (8)
        f32x4 a[2][2];
        #pragma unroll
        for (int qt = 0; qt < 2; ++qt)
            #pragma unroll
            for (int mt = 0; mt < 2; ++mt) {
                f32x4 s = cin[qt];
                s = __builtin_amdgcn_mfma_f32_16x16x32_bf16(kf2[mt][0], qf[qt][0], s, 0, 0, 0);
                s = __builtin_amdgcn_mfma_f32_16x16x32_bf16(kf2[mt][1], qf[qt][1], s, 0, 0, 0);
                a[qt][mt] = s;
            }
        // phase 2: exps + packs + lp partials + P-writes
        #pragma unroll
        for (int qt = 0; qt < 2; ++qt)
            #pragma unroll
            for (int mt = 0; mt < 2; ++mt) {
                const float p0 = fast_exp2(a[qt][mt][0]);
                const float p1 = fast_exp2(a[qt][mt][1]);
                const float p2 = fast_exp2(a[qt][mt][2]);
                const float p3 = fast_exp2(a[qt][mt][3]);
                lp4[qt] += (f32x4){p0, p1, p2, p3};
                const unsigned lo = __builtin_amdgcn_perm(__float_as_uint(p1), __float_as_uint(p0), 0x07060302u);
                const unsigned hi = __builtin_amdgcn_perm(__float_as_uint(p3), __float_as_uint(p2), 0x07060302u);
                *(uint2*)(pw[mt] + qt * 512) = make_uint2(lo, hi);
            }
        // phase 3: P reads, then all PV-MFMAs (8)
        short8 pf[2];
        #pragma unroll
        for (int qt = 0; qt < 2; ++qt)
            pf[qt] = *(const short8*)(pr + qt * 512);
        #pragma unroll
        for (int qt = 0; qt < 2; ++qt)
            #pragma unroll
            for (int ct = 0; ct < 4; ++ct)
                acc_o[qt][ct] = __builtin_amdgcn_mfma_f32_16x16x32_bf16(pf[qt], vf[ct], acc_o[qt][ct], 0, 0, 0);

        kp += 2048;
        vp += 2048;
    }

    float lp[2];
    #pragma unroll
    for (int qt = 0; qt < 2; ++qt) {
        lp[qt] = (lp4[qt][0] + lp4[qt][1]) + (lp4[qt][2] + lp4[qt][3]);
        lp[qt] += __shfl_xor(lp[qt], 16);
        lp[qt] += __shfl_xor(lp[qt], 32);
    }

    if (PARTIAL) {
        if (quad == 0) {
            #pragma unroll
            for (int qt = 0; qt < 2; ++qt)
                (Lbase + (size_t)h * 8 * SEQ)[(size_t)b * SEQ + s0 + 32 * w + 16 * qt + l15] = lp[qt];
        }
    } else {
        #pragma unroll
        for (int qt = 0; qt < 2; ++qt) {
            float inv[4];
            #pragma unroll
            for (int r = 0; r < 4; ++r) inv[r] = fast_rcp(__shfl(lp[qt], 4 * quad + r));
            #pragma unroll
            for (int ct = 0; ct < 4; ++ct)
                #pragma unroll
                for (int r = 0; r < 4; ++r) acc_o[qt][ct][r] *= inv[r];
        }
    }

    // ---- epilogue: four 16-channel chunks through the sP-overlay buffer ----
    unsigned short* Op = PARTIAL ? (Obf + (size_t)h * 8 * DIM * SEQ) : nullptr;
    const int mw = tid & 15, cgr = tid >> 4;   // 8 channel rows per pass
    for (int ctk = 0; ctk < 4; ++ctk) {
        __syncthreads();   // prior chunk reads done; at ctk==0 also: K-loop sP use done
        #pragma unroll
        for (int qt = 0; qt < 2; ++qt)
            #pragma unroll
            for (int r = 0; r < 4; ++r)
                sOc[l15 * LDO + 32 * w + 16 * qt + 4 * quad + r] = acc_o[qt][ctk][r];
        __syncthreads();
        #pragma unroll
        for (int i = 0; i < 2; ++i) {
            const int cl = cgr + 8 * i;
            const f32x4 v = *(const f32x4*)(sOc + cl * LDO + 4 * mw);
            if (PARTIAL) {
                *(ushort4*)(Op + ((size_t)b * DIM + 16 * ctk + cl) * SEQ + s0 + 4 * mw) =
                    make_ushort4(f2bf(v.x), f2bf(v.y), f2bf(v.z), f2bf(v.w));
            } else {
                *(f32x4*)(Out + ((size_t)b * DIM + 16 * ctk + cl) * SEQ + s0 + 4 * mw) = v;
            }
        }
    }
}

__global__ __launch_bounds__(256) void combine8(const unsigned short* __restrict__ Obf,
                                                const float* __restrict__ Lp,
                                                float* __restrict__ Out) {
    const int gid = blockIdx.x * 256 + threadIdx.x;
    const size_t base = (size_t)gid * 4;
    const int s = (int)(base & 4095);
    const int b = (int)(base >> 18);
    f32x4 os = (f32x4){0.f, 0.f, 0.f, 0.f};
    f32x4 ls = (f32x4){0.f, 0.f, 0.f, 0.f};
    #pragma unroll
    for (int h = 0; h < NSPLIT; ++h) {
        const ushort4 o = *(const ushort4*)(Obf + (size_t)h * 2097152 + base);
        os[0] += bf2f(o.x); os[1] += bf2f(o.y); os[2] += bf2f(o.z); os[3] += bf2f(o.w);
        const f32x4 l = *(const f32x4*)(Lp + (size_t)h * 8 * SEQ + b * SEQ + s);
        #pragma unroll
        for (int i = 0; i < 4; ++i) ls[i] += l[i];
    }
    f32x4 o;
    #pragma unroll
    for (int i = 0; i < 4; ++i) o[i] = os[i] / ls[i];
    *(f32x4*)(Out + base) = o;
}

__global__ __launch_bounds__(256, 2) void attn_fallback(const float* __restrict__ X,
                                                        float* __restrict__ Out) {
    __shared__ __align__(16) unsigned char smem[27648];
    unsigned short* sK = (unsigned short*)smem;
    unsigned short* sV = (unsigned short*)(smem + 9216);
    unsigned short* sP = (unsigned short*)(smem + 18432);
    float*          sO = (float*)smem;
    const int tid  = threadIdx.x;
    const int lane = tid & 63;
    const int w    = tid >> 6;
    const int l15  = lane & 15;
    const int quad = lane >> 4;
    const int b  = blockIdx.y;
    const int s0 = blockIdx.x * 64;
    const float* Xb = X + (size_t)b * DIM * SEQ;
    const int mgrp = tid & 15;
    const int c0   = tid >> 4;

    for (int cc = 0; cc < 4; ++cc) {
        int c = c0 + 16 * cc;
        const f32x4 v = *(const f32x4*)(Xb + (size_t)c * SEQ + s0 + 4 * mgrp);
        sK[(4 * mgrp + 0) * LDB + c] = f2bf(v.x);
        sK[(4 * mgrp + 1) * LDB + c] = f2bf(v.y);
        sK[(4 * mgrp + 2) * LDB + c] = f2bf(v.z);
        sK[(4 * mgrp + 3) * LDB + c] = f2bf(v.w);
    }
    __syncthreads();
    short8 qf0, qf1;
    {
        const int row = 16 * w + l15;
        qf0 = *(const short8*)(sK + row * LDB + quad * 8);
        qf1 = *(const short8*)(sK + row * LDB + 32 + quad * 8);
    }
    __syncthreads();
    f32x4 acc_o[4];
    for (int ct = 0; ct < 4; ++ct) acc_o[ct] = (f32x4){0.f, 0.f, 0.f, 0.f};
    float m_i[4] = {-1e30f, -1e30f, -1e30f, -1e30f};
    float l_i[4] = {0.f, 0.f, 0.f, 0.f};
    for (int kt = 0; kt < SEQ / 64; ++kt) {
        const int m0 = kt * 64;
        for (int cc = 0; cc < 4; ++cc) {
            int c = c0 + 16 * cc;
            const f32x4 v = *(const f32x4*)(Xb + (size_t)c * SEQ + m0 + 4 * mgrp);
            unsigned short h0 = f2bf(v.x), h1 = f2bf(v.y), h2 = f2bf(v.z), h3 = f2bf(v.w);
            *(ushort4*)(sV + c * LDB + 4 * mgrp) = make_ushort4(h0, h1, h2, h3);
            sK[(4 * mgrp + 0) * LDB + c] = h0;
            sK[(4 * mgrp + 1) * LDB + c] = h1;
            sK[(4 * mgrp + 2) * LDB + c] = h2;
            sK[(4 * mgrp + 3) * LDB + c] = h3;
        }
        __syncthreads();
        short8 vf[2][4];
        for (int ks = 0; ks < 2; ++ks)
            for (int ct = 0; ct < 4; ++ct)
                vf[ks][ct] = *(const short8*)(sV + (16 * ct + l15) * LDB + ks * 32 + quad * 8);
        f32x4 acc_s[4];
        for (int mt = 0; mt < 4; ++mt) {
            const int row = 16 * mt + l15;
            const short8 kf0 = *(const short8*)(sK + row * LDB + quad * 8);
            const short8 kf1 = *(const short8*)(sK + row * LDB + 32 + quad * 8);
            f32x4 a = (f32x4){0.f, 0.f, 0.f, 0.f};
            a = __builtin_amdgcn_mfma_f32_16x16x32_bf16(qf0, kf0, a, 0, 0, 0);
            a = __builtin_amdgcn_mfma_f32_16x16x32_bf16(qf1, kf1, a, 0, 0, 0);
            acc_s[mt] = a;
        }
        float alpha[4];
        for (int r = 0; r < 4; ++r) {
            float mx = fmaxf(fmaxf(acc_s[0][r], acc_s[1][r]), fmaxf(acc_s[2][r], acc_s[3][r]));
            mx = fmaxf(mx, __shfl_xor(mx, 1));
            mx = fmaxf(mx, __shfl_xor(mx, 2));
            mx = fmaxf(mx, __shfl_xor(mx, 4));
            mx = fmaxf(mx, __shfl_xor(mx, 8));
            const float mnew = fmaxf(m_i[r], mx);
            alpha[r] = __expf(m_i[r] - mnew);
            m_i[r] = mnew;
        }
        float rowsum[4] = {0.f, 0.f, 0.f, 0.f};
        unsigned short pb[4][4];
        for (int mt = 0; mt < 4; ++mt)
            for (int r = 0; r < 4; ++r) {
                const float p = __expf(acc_s[mt][r] - m_i[r]);
                rowsum[r] += p;
                pb[mt][r] = f2bf(p);
            }
        for (int r = 0; r < 4; ++r) {
            float s = rowsum[r];
            s += __shfl_xor(s, 1);
            s += __shfl_xor(s, 2);
            s += __shfl_xor(s, 4);
            s += __shfl_xor(s, 8);
            l_i[r] = alpha[r] * l_i[r] + s;
        }
        for (int ct = 0; ct < 4; ++ct)
            for (int r = 0; r < 4; ++r)
                acc_o[ct][r] *= alpha[r];
        for (int mt = 0; mt < 4; ++mt)
            for (int r = 0; r < 4; ++r)
                sP[(16 * w + quad * 4 + r) * LDB + l15 + 16 * mt] = pb[mt][r];
        __syncthreads();
        const short8 pf0 = *(const short8*)(sP + (16 * w + l15) * LDB + quad * 8);
        const short8 pf1 = *(const short8*)(sP + (16 * w + l15) * LDB + 32 + quad * 8);
        for (int ct = 0; ct < 4; ++ct) {
            acc_o[ct] = __builtin_amdgcn_mfma_f32_16x16x32_bf16(pf0, vf[0][ct], acc_o[ct], 0, 0, 0);
            acc_o[ct] = __builtin_amdgcn_mfma_f32_16x16x32_bf16(pf1, vf[1][ct], acc_o[ct], 0, 0, 0);
        }
    }
    float inv[4];
    for (int r = 0; r < 4; ++r) inv[r] = 1.f / l_i[r];
    for (int ct = 0; ct < 4; ++ct) {
        const int c = 16 * ct + l15;
        for (int r = 0; r < 4; ++r)
            sO[c * LDO + 16 * w + quad * 4 + r] = acc_o[ct][r] * inv[r];
    }
    __syncthreads();
    for (int cc = 0; cc < 4; ++cc) {
        const int c = c0 + 16 * cc;
        const f32x4 v = *(const f32x4*)(sO + c * LDO + 4 * mgrp);
        *(f32x4*)(Out + (size_t)b * DIM * SEQ + (size_t)c * SEQ + s0 + 4 * mgrp) = v;
    }
}

extern "C" void kernel_launch(void* const* d_in, const int* in_sizes, int n_in,
                              void* d_out, int out_size, void* d_ws, size_t ws_size,
                              hipStream_t stream) {
    const float* X = (const float*)d_in[0];
    float* Out = (float*)d_out;
    const size_t elems = (size_t)8 * SEQ * DIM;               // 2M
    const size_t offVf    = elems * 2;                        // Kf 4MB
    const size_t offNorms = offVf + elems * 2;                // Vf 4MB -> 8MB
    const size_t offMaxP  = offNorms + (size_t)8 * SEQ * 4;   // +128KB
    const size_t offObf   = offMaxP + 8 * 64 * 4;             // +2KB
    const size_t offLp    = offObf + (size_t)NSPLIT * elems * 2;      // +32MB (8 bf16 slabs)
    const size_t need     = offLp + (size_t)NSPLIT * 8 * SEQ * 4;     // ~41.2MB

    if (ws_size >= need) {
        unsigned short* Kf = (unsigned short*)d_ws;
        unsigned short* Vf = (unsigned short*)((char*)d_ws + offVf);
        float* Norms   = (float*)((char*)d_ws + offNorms);
        float* MaxPart = (float*)((char*)d_ws + offMaxP);
        unsigned short* Obf = (unsigned short*)((char*)d_ws + offObf);
        float* Lp = (float*)((char*)d_ws + offLp);
        prepass4<<<dim3(64, 8), 256, 0, stream>>>(X, Kf, Vf, Norms, MaxPart);
        attn_split4<true><<<dim3(64, 8, NSPLIT), 128, 0, stream>>>(Kf, Vf, Norms, MaxPart,
                                                                   Obf, Lp, nullptr,
                                                                   64 / NSPLIT * 2);   // 16 iters
        combine8<<<(int)(elems / 1024), 256, 0, stream>>>(Obf, Lp, Out);
    } else {
        attn_fallback<<<dim3(64, 8), 256, 0, stream>>>(X, Out);
    }
}

// Round 14
// 124.999 us; speedup vs baseline: 4.0691x; 4.0691x over previous
//
#include <hip/hip_runtime.h>
#include <math.h>

// Non-local attention: X [8, 64, 64, 64] fp32.
// Per batch b: Q=K=V = X_b^T  [S=4096, D=64];  out = softmax(Q K^T) V, stored [b][c][s].
//
// R14 = R13 with the launch-bounds spill fixed: (128,8) capped VGPR at 64 -> allocator
// hit 32 -> 1.8GB scratch spill (R13 WRITE_SIZE tell). (128,4) caps at 128; the loop
// uses ~60 VGPR, so HW still reaches 8 waves/SIMD = 16 blocks/CU.
//  - split-K x8, 4096 blocks; LDS 4608 B (chunked epilogue over sP)
//  - R10 compiler-scheduled loop (beats manual pipelines R11/R12)
//  - fragment-order global K/V streams, raw v_exp_f32, C-S bound in MFMA C-init

#define SEQ 4096
#define DIM 64
#define LDB 72
#define LDO 68
#define LDS2 68
#define NSPLIT 8
#define QSCALE 1.2011224087864498f   // sqrt(log2(e))

typedef __attribute__((ext_vector_type(8))) short  short8;
typedef __attribute__((ext_vector_type(4))) float  f32x4;

__device__ __forceinline__ unsigned short f2bf(float f) {
    union { float f; unsigned int u; } x; x.f = f;
    unsigned int u = x.u + 0x7FFFu + ((x.u >> 16) & 1u);
    return (unsigned short)(u >> 16);
}
__device__ __forceinline__ float bf2f(unsigned short h) {
    union { unsigned int u; float f; } x; x.u = ((unsigned int)h) << 16; return x.f;
}
__device__ __forceinline__ float fast_exp2(float x) {
#if __has_builtin(__builtin_amdgcn_exp2f)
    return __builtin_amdgcn_exp2f(x);
#else
    float r;
    asm("v_exp_f32 %0, %1\n\ts_nop 0" : "=v"(r) : "v"(x));
    return r;
#endif
}
__device__ __forceinline__ float fast_rcp(float x) {
#if __has_builtin(__builtin_amdgcn_rcpf)
    return __builtin_amdgcn_rcpf(x);
#else
    return 1.f / x;
#endif
}

// ---------------- prepass: fragment-order bf16 arrays + scaled norms + max partials ----
__global__ __launch_bounds__(256) void prepass4(const float* __restrict__ X,
                                                unsigned short* __restrict__ Kf,
                                                unsigned short* __restrict__ Vf,
                                                float* __restrict__ Norms,
                                                float* __restrict__ MaxPart) {
    __shared__ __align__(16) unsigned short sT[64 * LDS2];    // scaled [m][c]
    __shared__ __align__(16) unsigned short sVu[64 * LDS2];   // unscaled [c][m]
    __shared__ float sRed[4];
    const int b = blockIdx.y, m0 = blockIdx.x * 64;
    const float* Xb = X + (size_t)b * DIM * SEQ;
    const int t = threadIdx.x, w = t >> 6;
    const int mw = t & 15, cg = t >> 4;

    #pragma unroll
    for (int cr = 0; cr < 4; ++cr) {
        const int c = cg * 4 + cr;
        const f32x4 v = *(const f32x4*)(Xb + (size_t)c * SEQ + m0 + 4 * mw);
        *(ushort4*)(sVu + c * LDS2 + 4 * mw) =
            make_ushort4(f2bf(v.x), f2bf(v.y), f2bf(v.z), f2bf(v.w));
        sT[(4 * mw + 0) * LDS2 + c] = f2bf(v.x * QSCALE);
        sT[(4 * mw + 1) * LDS2 + c] = f2bf(v.y * QSCALE);
        sT[(4 * mw + 2) * LDS2 + c] = f2bf(v.z * QSCALE);
        sT[(4 * mw + 3) * LDS2 + c] = f2bf(v.w * QSCALE);
    }
    __syncthreads();
    const int m = t >> 2, ck = t & 3;   // m: key row (for Kf) AND chan row (for Vf)

    const short8 a0 = *(const short8*)(sT + m * LDS2 + ck * 16);
    const short8 a1 = *(const short8*)(sT + m * LDS2 + ck * 16 + 8);
    {
        const size_t base = (size_t)b * 262144 + (size_t)(m0 >> 5) * 2048;  // shorts
        #pragma unroll
        for (int j = 0; j < 2; ++j) {
            const int chunk = 2 * ck + j;
            const int tile = m >> 5, mt = (m >> 4) & 1;
            const int quad = chunk & 3, ks = chunk >> 2;
            const size_t off = base + (size_t)(tile * 4 + mt * 2 + ks) * 512
                                    + (size_t)(quad * 16 + (m & 15)) * 8;
            *(short8*)(Kf + off) = j ? a1 : a0;
        }
    }
    float s = 0.f;
    #pragma unroll
    for (int i = 0; i < 8; ++i) {
        const float f0 = bf2f((unsigned short)a0[i]);
        const float f1 = bf2f((unsigned short)a1[i]);
        s += f0 * f0 + f1 * f1;
    }
    s += __shfl_xor(s, 1);
    s += __shfl_xor(s, 2);
    const float nm = sqrtf(s);
    if (ck == 0) Norms[(size_t)b * SEQ + m0 + m] = nm;

    const short8 v0 = *(const short8*)(sVu + m * LDS2 + ck * 16);
    const short8 v1 = *(const short8*)(sVu + m * LDS2 + ck * 16 + 8);
    {
        const size_t base = (size_t)b * 262144;
        #pragma unroll
        for (int j = 0; j < 2; ++j) {
            const int chunk = 2 * ck + j;
            const int tile = chunk >> 2, quad = chunk & 3;
            const size_t off = base + (size_t)((m0 >> 5) + tile) * 2048
                                    + (size_t)((m >> 4) * 64 + quad * 16 + (m & 15)) * 8;
            *(short8*)(Vf + off) = j ? v1 : v0;
        }
    }

    float mx = nm;
    #pragma unroll
    for (int d = 4; d < 64; d <<= 1) mx = fmaxf(mx, __shfl_xor(mx, d));
    if ((t & 63) == 0) sRed[w] = mx;
    __syncthreads();
    if (t == 0)
        MaxPart[b * 64 + blockIdx.x] =
            fmaxf(fmaxf(sRed[0], sRed[1]), fmaxf(sRed[2], sRed[3]));
}

// BN=32 flash kernel, 2 waves x 32 Q rows, split-K x8. Fragment-order global K/V.
// LDS 4608 B: sP (wave-private P strips, 4KB) overlaid by the 16-channel epilogue buffer.
template <bool PARTIAL>
__global__ __launch_bounds__(128, 4) void attn_split4(const unsigned short* __restrict__ Kf,
                                                      const unsigned short* __restrict__ Vf,
                                                      const float* __restrict__ Norms,
                                                      const float* __restrict__ MaxPart,
                                                      unsigned short* __restrict__ Obf,  // PARTIAL
                                                      float* __restrict__ Lbase,         // PARTIAL
                                                      float* __restrict__ Out,           // !PARTIAL
                                                      int niter) {
    __shared__ __align__(16) unsigned char smem[4608];
    unsigned short* sP = (unsigned short*)smem;   // [wave][row n 0..31][32 shorts] = 4KB
    float*          sOc = (float*)smem;           // epilogue overlay: 16 ch x LDO fp32 (4352B)

    const int tid  = threadIdx.x;
    const int lane = tid & 63;
    const int w    = tid >> 6;
    const int l15  = lane & 15;
    const int quad = lane >> 4;

    const int b   = blockIdx.y;
    const int s0  = blockIdx.x * 64;
    const int h   = blockIdx.z;
    const int kt0 = h * niter;
    const unsigned short* Kfb = Kf + (size_t)b * 262144;
    const unsigned short* Vfb = Vf + (size_t)b * 262144;

    float mxn = MaxPart[b * 64 + lane];
    #pragma unroll
    for (int d = 1; d < 64; d <<= 1) mxn = fmaxf(mxn, __shfl_xor(mxn, d));

    // Q frags from Kf (scaled): row = s0+32w+16qt+l15 -> tile=(s0+32w)>>5, mt=qt
    short8 qf[2][2];
    f32x4 cin[2];
    const int qtile = (s0 + 32 * w) >> 5;
    #pragma unroll
    for (int qt = 0; qt < 2; ++qt) {
        #pragma unroll
        for (int ks = 0; ks < 2; ++ks)
            qf[qt][ks] = *(const short8*)(Kfb + (size_t)(qtile * 4 + qt * 2 + ks) * 512 + lane * 8);
        const float mrow = Norms[(size_t)b * SEQ + s0 + 32 * w + 16 * qt + l15] * mxn;
        cin[qt] = (f32x4){-mrow, -mrow, -mrow, -mrow};
    }

    f32x4 acc_o[2][4];
    #pragma unroll
    for (int qt = 0; qt < 2; ++qt)
        #pragma unroll
        for (int ct = 0; ct < 4; ++ct) acc_o[qt][ct] = (f32x4){0.f, 0.f, 0.f, 0.f};
    f32x4 lp4[2];
    lp4[0] = (f32x4){0.f, 0.f, 0.f, 0.f};
    lp4[1] = (f32x4){0.f, 0.f, 0.f, 0.f};

    // ---- P LDS addresses (wave-private; swizzle verified R8) ----
    const int vkey = (l15 & 3) ^ (l15 >> 2);
    unsigned short* const prow = sP + (w << 10) + (l15 << 5);     // +qt*512
    unsigned short* pw[2];
    #pragma unroll
    for (int mt = 0; mt < 2; ++mt)
        pw[mt] = prow + ((((2 * mt + (quad >> 1)) ^ vkey) << 3) + ((quad & 1) << 2));
    const unsigned short* pr = prow + ((quad ^ vkey) << 3);

    // ---- fragment stream pointers (lane-contiguous 1KB per load) ----
    const unsigned short* kp = Kfb + (size_t)kt0 * 2048 + lane * 8;
    const unsigned short* vp = Vfb + (size_t)kt0 * 2048 + lane * 8;

    for (int it = 0; it < niter; ++it) {
        short8 kf2[2][2], vf[4];
        #pragma unroll
        for (int mt = 0; mt < 2; ++mt)
            #pragma unroll
            for (int ks = 0; ks < 2; ++ks)
                kf2[mt][ks] = *(const short8*)(kp + (mt * 2 + ks) * 512);
        #pragma unroll
        for (int ct = 0; ct < 4; ++ct)
            vf[ct] = *(const short8*)(vp + ct * 512);

        // phase 1: all S-MFMAs (8)
        f32x4 a[2][2];
        #pragma unroll
        for (int qt = 0; qt < 2; ++qt)
            #pragma unroll
            for (int mt = 0; mt < 2; ++mt) {
                f32x4 s = cin[qt];
                s = __builtin_amdgcn_mfma_f32_16x16x32_bf16(kf2[mt][0], qf[qt][0], s, 0, 0, 0);
                s = __builtin_amdgcn_mfma_f32_16x16x32_bf16(kf2[mt][1], qf[qt][1], s, 0, 0, 0);
                a[qt][mt] = s;
            }
        // phase 2: exps + packs + lp partials + P-writes
        #pragma unroll
        for (int qt = 0; qt < 2; ++qt)
            #pragma unroll
            for (int mt = 0; mt < 2; ++mt) {
                const float p0 = fast_exp2(a[qt][mt][0]);
                const float p1 = fast_exp2(a[qt][mt][1]);
                const float p2 = fast_exp2(a[qt][mt][2]);
                const float p3 = fast_exp2(a[qt][mt][3]);
                lp4[qt] += (f32x4){p0, p1, p2, p3};
                const unsigned lo = __builtin_amdgcn_perm(__float_as_uint(p1), __float_as_uint(p0), 0x07060302u);
                const unsigned hi = __builtin_amdgcn_perm(__float_as_uint(p3), __float_as_uint(p2), 0x07060302u);
                *(uint2*)(pw[mt] + qt * 512) = make_uint2(lo, hi);
            }
        // phase 3: P reads, then all PV-MFMAs (8)
        short8 pf[2];
        #pragma unroll
        for (int qt = 0; qt < 2; ++qt)
            pf[qt] = *(const short8*)(pr + qt * 512);
        #pragma unroll
        for (int qt = 0; qt < 2; ++qt)
            #pragma unroll
            for (int ct = 0; ct < 4; ++ct)
                acc_o[qt][ct] = __builtin_amdgcn_mfma_f32_16x16x32_bf16(pf[qt], vf[ct], acc_o[qt][ct], 0, 0, 0);

        kp += 2048;
        vp += 2048;
    }

    float lp[2];
    #pragma unroll
    for (int qt = 0; qt < 2; ++qt) {
        lp[qt] = (lp4[qt][0] + lp4[qt][1]) + (lp4[qt][2] + lp4[qt][3]);
        lp[qt] += __shfl_xor(lp[qt], 16);
        lp[qt] += __shfl_xor(lp[qt], 32);
    }

    if (PARTIAL) {
        if (quad == 0) {
            #pragma unroll
            for (int qt = 0; qt < 2; ++qt)
                (Lbase + (size_t)h * 8 * SEQ)[(size_t)b * SEQ + s0 + 32 * w + 16 * qt + l15] = lp[qt];
        }
    } else {
        #pragma unroll
        for (int qt = 0; qt < 2; ++qt) {
            float inv[4];
            #pragma unroll
            for (int r = 0; r < 4; ++r) inv[r] = fast_rcp(__shfl(lp[qt], 4 * quad + r));
            #pragma unroll
            for (int ct = 0; ct < 4; ++ct)
                #pragma unroll
                for (int r = 0; r < 4; ++r) acc_o[qt][ct][r] *= inv[r];
        }
    }

    // ---- epilogue: four 16-channel chunks through the sP-overlay buffer ----
    unsigned short* Op = PARTIAL ? (Obf + (size_t)h * 8 * DIM * SEQ) : nullptr;
    const int mw = tid & 15, cgr = tid >> 4;   // 8 channel rows per pass
    for (int ctk = 0; ctk < 4; ++ctk) {
        __syncthreads();   // prior chunk reads done; at ctk==0 also: K-loop sP use done
        #pragma unroll
        for (int qt = 0; qt < 2; ++qt)
            #pragma unroll
            for (int r = 0; r < 4; ++r)
                sOc[l15 * LDO + 32 * w + 16 * qt + 4 * quad + r] = acc_o[qt][ctk][r];
        __syncthreads();
        #pragma unroll
        for (int i = 0; i < 2; ++i) {
            const int cl = cgr + 8 * i;
            const f32x4 v = *(const f32x4*)(sOc + cl * LDO + 4 * mw);
            if (PARTIAL) {
                *(ushort4*)(Op + ((size_t)b * DIM + 16 * ctk + cl) * SEQ + s0 + 4 * mw) =
                    make_ushort4(f2bf(v.x), f2bf(v.y), f2bf(v.z), f2bf(v.w));
            } else {
                *(f32x4*)(Out + ((size_t)b * DIM + 16 * ctk + cl) * SEQ + s0 + 4 * mw) = v;
            }
        }
    }
}

__global__ __launch_bounds__(256) void combine8(const unsigned short* __restrict__ Obf,
                                                const float* __restrict__ Lp,
                                                float* __restrict__ Out) {
    const int gid = blockIdx.x * 256 + threadIdx.x;
    const size_t base = (size_t)gid * 4;
    const int s = (int)(base & 4095);
    const int b = (int)(base >> 18);
    f32x4 os = (f32x4){0.f, 0.f, 0.f, 0.f};
    f32x4 ls = (f32x4){0.f, 0.f, 0.f, 0.f};
    #pragma unroll
    for (int h = 0; h < NSPLIT; ++h) {
        const ushort4 o = *(const ushort4*)(Obf + (size_t)h * 2097152 + base);
        os[0] += bf2f(o.x); os[1] += bf2f(o.y); os[2] += bf2f(o.z); os[3] += bf2f(o.w);
        const f32x4 l = *(const f32x4*)(Lp + (size_t)h * 8 * SEQ + b * SEQ + s);
        #pragma unroll
        for (int i = 0; i < 4; ++i) ls[i] += l[i];
    }
    f32x4 o;
    #pragma unroll
    for (int i = 0; i < 4; ++i) o[i] = os[i] / ls[i];
    *(f32x4*)(Out + base) = o;
}

__global__ __launch_bounds__(256, 2) void attn_fallback(const float* __restrict__ X,
                                                        float* __restrict__ Out) {
    __shared__ __align__(16) unsigned char smem[27648];
    unsigned short* sK = (unsigned short*)smem;
    unsigned short* sV = (unsigned short*)(smem + 9216);
    unsigned short* sP = (unsigned short*)(smem + 18432);
    float*          sO = (float*)smem;
    const int tid  = threadIdx.x;
    const int lane = tid & 63;
    const int w    = tid >> 6;
    const int l15  = lane & 15;
    const int quad = lane >> 4;
    const int b  = blockIdx.y;
    const int s0 = blockIdx.x * 64;
    const float* Xb = X + (size_t)b * DIM * SEQ;
    const int mgrp = tid & 15;
    const int c0   = tid >> 4;

    for (int cc = 0; cc < 4; ++cc) {
        int c = c0 + 16 * cc;
        const f32x4 v = *(const f32x4*)(Xb + (size_t)c * SEQ + s0 + 4 * mgrp);
        sK[(4 * mgrp + 0) * LDB + c] = f2bf(v.x);
        sK[(4 * mgrp + 1) * LDB + c] = f2bf(v.y);
        sK[(4 * mgrp + 2) * LDB + c] = f2bf(v.z);
        sK[(4 * mgrp + 3) * LDB + c] = f2bf(v.w);
    }
    __syncthreads();
    short8 qf0, qf1;
    {
        const int row = 16 * w + l15;
        qf0 = *(const short8*)(sK + row * LDB + quad * 8);
        qf1 = *(const short8*)(sK + row * LDB + 32 + quad * 8);
    }
    __syncthreads();
    f32x4 acc_o[4];
    for (int ct = 0; ct < 4; ++ct) acc_o[ct] = (f32x4){0.f, 0.f, 0.f, 0.f};
    float m_i[4] = {-1e30f, -1e30f, -1e30f, -1e30f};
    float l_i[4] = {0.f, 0.f, 0.f, 0.f};
    for (int kt = 0; kt < SEQ / 64; ++kt) {
        const int m0 = kt * 64;
        for (int cc = 0; cc < 4; ++cc) {
            int c = c0 + 16 * cc;
            const f32x4 v = *(const f32x4*)(Xb + (size_t)c * SEQ + m0 + 4 * mgrp);
            unsigned short h0 = f2bf(v.x), h1 = f2bf(v.y), h2 = f2bf(v.z), h3 = f2bf(v.w);
            *(ushort4*)(sV + c * LDB + 4 * mgrp) = make_ushort4(h0, h1, h2, h3);
            sK[(4 * mgrp + 0) * LDB + c] = h0;
            sK[(4 * mgrp + 1) * LDB + c] = h1;
            sK[(4 * mgrp + 2) * LDB + c] = h2;
            sK[(4 * mgrp + 3) * LDB + c] = h3;
        }
        __syncthreads();
        short8 vf[2][4];
        for (int ks = 0; ks < 2; ++ks)
            for (int ct = 0; ct < 4; ++ct)
                vf[ks][ct] = *(const short8*)(sV + (16 * ct + l15) * LDB + ks * 32 + quad * 8);
        f32x4 acc_s[4];
        for (int mt = 0; mt < 4; ++mt) {
            const int row = 16 * mt + l15;
            const short8 kf0 = *(const short8*)(sK + row * LDB + quad * 8);
            const short8 kf1 = *(const short8*)(sK + row * LDB + 32 + quad * 8);
            f32x4 a = (f32x4){0.f, 0.f, 0.f, 0.f};
            a = __builtin_amdgcn_mfma_f32_16x16x32_bf16(qf0, kf0, a, 0, 0, 0);
            a = __builtin_amdgcn_mfma_f32_16x16x32_bf16(qf1, kf1, a, 0, 0, 0);
            acc_s[mt] = a;
        }
        float alpha[4];
        for (int r = 0; r < 4; ++r) {
            float mx = fmaxf(fmaxf(acc_s[0][r], acc_s[1][r]), fmaxf(acc_s[2][r], acc_s[3][r]));
            mx = fmaxf(mx, __shfl_xor(mx, 1));
            mx = fmaxf(mx, __shfl_xor(mx, 2));
            mx = fmaxf(mx, __shfl_xor(mx, 4));
            mx = fmaxf(mx, __shfl_xor(mx, 8));
            const float mnew = fmaxf(m_i[r], mx);
            alpha[r] = __expf(m_i[r] - mnew);
            m_i[r] = mnew;
        }
        float rowsum[4] = {0.f, 0.f, 0.f, 0.f};
        unsigned short pb[4][4];
        for (int mt = 0; mt < 4; ++mt)
            for (int r = 0; r < 4; ++r) {
                const float p = __expf(acc_s[mt][r] - m_i[r]);
                rowsum[r] += p;
                pb[mt][r] = f2bf(p);
            }
        for (int r = 0; r < 4; ++r) {
            float s = rowsum[r];
            s += __shfl_xor(s, 1);
            s += __shfl_xor(s, 2);
            s += __shfl_xor(s, 4);
            s += __shfl_xor(s, 8);
            l_i[r] = alpha[r] * l_i[r] + s;
        }
        for (int ct = 0; ct < 4; ++ct)
            for (int r = 0; r < 4; ++r)
                acc_o[ct][r] *= alpha[r];
        for (int mt = 0; mt < 4; ++mt)
            for (int r = 0; r < 4; ++r)
                sP[(16 * w + quad * 4 + r) * LDB + l15 + 16 * mt] = pb[mt][r];
        __syncthreads();
        const short8 pf0 = *(const short8*)(sP + (16 * w + l15) * LDB + quad * 8);
        const short8 pf1 = *(const short8*)(sP + (16 * w + l15) * LDB + 32 + quad * 8);
        for (int ct = 0; ct < 4; ++ct) {
            acc_o[ct] = __builtin_amdgcn_mfma_f32_16x16x32_bf16(pf0, vf[0][ct], acc_o[ct], 0, 0, 0);
            acc_o[ct] = __builtin_amdgcn_mfma_f32_16x16x32_bf16(pf1, vf[1][ct], acc_o[ct], 0, 0, 0);
        }
    }
    float inv[4];
    for (int r = 0; r < 4; ++r) inv[r] = 1.f / l_i[r];
    for (int ct = 0; ct < 4; ++ct) {
        const int c = 16 * ct + l15;
        for (int r = 0; r < 4; ++r)
            sO[c * LDO + 16 * w + quad * 4 + r] = acc_o[ct][r] * inv[r];
    }
    __syncthreads();
    for (int cc = 0; cc < 4; ++cc) {
        const int c = c0 + 16 * cc;
        const f32x4 v = *(const f32x4*)(sO + c * LDO + 4 * mgrp);
        *(f32x4*)(Out + (size_t)b * DIM * SEQ + (size_t)c * SEQ + s0 + 4 * mgrp) = v;
    }
}

extern "C" void kernel_launch(void* const* d_in, const int* in_sizes, int n_in,
                              void* d_out, int out_size, void* d_ws, size_t ws_size,
                              hipStream_t stream) {
    const float* X = (const float*)d_in[0];
    float* Out = (float*)d_out;
    const size_t elems = (size_t)8 * SEQ * DIM;               // 2M
    const size_t offVf    = elems * 2;                        // Kf 4MB
    const size_t offNorms = offVf + elems * 2;                // Vf 4MB -> 8MB
    const size_t offMaxP  = offNorms + (size_t)8 * SEQ * 4;   // +128KB
    const size_t offObf   = offMaxP + 8 * 64 * 4;             // +2KB
    const size_t offLp    = offObf + (size_t)NSPLIT * elems * 2;      // +32MB (8 bf16 slabs)
    const size_t need     = offLp + (size_t)NSPLIT * 8 * SEQ * 4;     // ~41.2MB

    if (ws_size >= need) {
        unsigned short* Kf = (unsigned short*)d_ws;
        unsigned short* Vf = (unsigned short*)((char*)d_ws + offVf);
        float* Norms   = (float*)((char*)d_ws + offNorms);
        float* MaxPart = (float*)((char*)d_ws + offMaxP);
        unsigned short* Obf = (unsigned short*)((char*)d_ws + offObf);
        float* Lp = (float*)((char*)d_ws + offLp);
        prepass4<<<dim3(64, 8), 256, 0, stream>>>(X, Kf, Vf, Norms, MaxPart);
        attn_split4<true><<<dim3(64, 8, NSPLIT), 128, 0, stream>>>(Kf, Vf, Norms, MaxPart,
                                                                   Obf, Lp, nullptr,
                                                                   128 / NSPLIT);   // 16 iters
        combine8<<<(int)(elems / 1024), 256, 0, stream>>>(Obf, Lp, Out);
    } else {
        attn_fallback<<<dim3(64, 8), 256, 0, stream>>>(X, Out);
    }
}